// Round 2
// baseline (395.955 us; speedup 1.0000x reference)
//
#include <hip/hip_runtime.h>
#include <math.h>

// Problem constants
#define N_ 16
#define T_ 8192
#define C_ 128
#define K_ 64

// main kernel tiling
#define BPN 64   // blocks per n
#define TPB 128  // t per block
#define TILE 32  // t per LDS tile

// ws layout in floats
#define WS_VLAD 0              // N*K*C = 131072
#define WS_ASUM 131072         // N*K  = 1024
#define WS_GSUM 132096         // N    = 16 (+ pad)
#define WS_ZEND 132608         // zeroed region end
#define WS_RNORM 132608        // N*T = 131072

__global__ void zero_ws(float* ws) {
    int i = blockIdx.x * 256 + threadIdx.x;
    if (i < WS_ZEND) ws[i] = 0.0f;
}

// 1 / max(||x[n,t,:]||, 1e-12), one wave per (n,t) row
__global__ void rnorm_k(const float* __restrict__ x, float* __restrict__ ws) {
    int row = blockIdx.x * 4 + (threadIdx.x >> 6);
    int lane = threadIdx.x & 63;
    const float* xr = x + (size_t)row * C_;
    float a = xr[lane], b = xr[lane + 64];
    float ss = a * a + b * b;
#pragma unroll
    for (int m = 1; m < 64; m <<= 1) ss += __shfl_xor(ss, m, 64);
    if (lane == 0) ws[WS_RNORM + row] = 1.0f / fmaxf(sqrtf(ss), 1e-12f);
}

// Fused: normalize -> dwconv3 -> bn1+relu -> 1x1 conv (w2 in REGISTERS)
// -> bn2+relu -> mask -> softmax over K -> accumulate vlad + asum.
__global__ __launch_bounds__(256, 4) void main_k(
    const float* __restrict__ x,
    const float* __restrict__ conv1_w,
    const float* __restrict__ bn1_g, const float* __restrict__ bn1_b,
    const float* __restrict__ bn1_m, const float* __restrict__ bn1_v,
    const float* __restrict__ conv2_w, const float* __restrict__ conv2_b,
    const float* __restrict__ bn2_g, const float* __restrict__ bn2_b,
    const float* __restrict__ bn2_m, const float* __restrict__ bn2_v,
    const int* __restrict__ length,
    float* __restrict__ ws) {

    __shared__ __align__(16) float hs[TILE][C_];       // 16 KB
    __shared__ __align__(16) float atile[TILE][68];    // 8.7 KB
    __shared__ __align__(16) float scale1[C_], shift1[C_];
    __shared__ __align__(16) float w1a[C_], w1b[C_], w1c[C_];
    __shared__ float scale2[K_], shift2[K_], rtile[TILE];

    const int tid = threadIdx.x;
    const int n = blockIdx.x / BPN;
    const int tb = (blockIdx.x % BPN) * TPB;

    for (int i = tid; i < C_; i += 256) {
        float s = bn1_g[i] * rsqrtf(bn1_v[i] + 1e-5f);
        scale1[i] = s;
        shift1[i] = bn1_b[i] - bn1_m[i] * s;
        w1a[i] = conv1_w[i * 9 + 1];  // kh=0, kw=1
        w1b[i] = conv1_w[i * 9 + 4];  // kh=1, kw=1
        w1c[i] = conv1_w[i * 9 + 7];  // kh=2, kw=1
    }
    if (tid < K_) {
        float s = bn2_g[tid] * rsqrtf(bn2_v[tid] + 1e-5f);
        scale2[tid] = s;
        shift2[tid] = s * conv2_b[tid] + bn2_b[tid] - bn2_m[tid] * s;
    }

    const int kk = tid >> 4, cc = tid & 15;
    const int k0 = kk * 4, c0 = cc * 8;

    // conv2 weights live in registers: this thread's 4k x 8c tile
    float4 w2r[4][2];
#pragma unroll
    for (int i = 0; i < 4; ++i) {
        w2r[i][0] = *(const float4*)&conv2_w[(k0 + i) * C_ + c0];
        w2r[i][1] = *(const float4*)&conv2_w[(k0 + i) * C_ + c0 + 4];
    }

    const int L = length[n];
    const float* rn = ws + WS_RNORM + (size_t)n * T_;
    const float* xb = x + (size_t)n * T_ * C_;

    float acc[4][8];
#pragma unroll
    for (int i = 0; i < 4; ++i)
#pragma unroll
        for (int j = 0; j < 8; ++j) acc[i][j] = 0.0f;
    float asum = 0.0f;

    __syncthreads();

    float sc2[4], sh2[4];
#pragma unroll
    for (int i = 0; i < 4; ++i) { sc2[i] = scale2[k0 + i]; sh2[i] = shift2[k0 + i]; }

    const int att = tid >> 3;          // A1: row within tile (0..31)
    const int ac0 = (tid & 7) * 16;    // A1: col base

    for (int tile = 0; tile < TPB / TILE; ++tile) {
        const int tbase = tb + tile * TILE;

        // ---- A1: compute h for 32 t's in parallel into LDS ----
        {
            const int t = tbase + att;
            float r0 = rn[t];
            float rm = (t > 0) ? rn[t - 1] : 0.f;
            float rp = (t < T_ - 1) ? rn[t + 1] : 0.f;
            if ((tid & 7) == 0) rtile[att] = r0;
            const float* xr = xb + (size_t)t * C_;
#pragma unroll
            for (int i = 0; i < 4; ++i) {
                const int c = ac0 + i * 4;
                float4 xc = *(const float4*)&xr[c];
                float4 xm = {0.f, 0.f, 0.f, 0.f}, xp = {0.f, 0.f, 0.f, 0.f};
                if (t > 0) xm = *(const float4*)&xr[c - C_];
                if (t < T_ - 1) xp = *(const float4*)&xr[c + C_];
                float4 wa = *(const float4*)&w1a[c];
                float4 wb = *(const float4*)&w1b[c];
                float4 wc = *(const float4*)&w1c[c];
                float4 s1 = *(const float4*)&scale1[c];
                float4 b1 = *(const float4*)&shift1[c];
                float4 h;
                h.x = fmaxf(0.f, (xm.x * rm * wa.x + xc.x * r0 * wb.x + xp.x * rp * wc.x) * s1.x + b1.x);
                h.y = fmaxf(0.f, (xm.y * rm * wa.y + xc.y * r0 * wb.y + xp.y * rp * wc.y) * s1.y + b1.y);
                h.z = fmaxf(0.f, (xm.z * rm * wa.z + xc.z * r0 * wb.z + xp.z * rp * wc.z) * s1.z + b1.z);
                h.w = fmaxf(0.f, (xm.w * rm * wa.w + xc.w * r0 * wb.w + xp.w * rp * wc.w) * s1.w + b1.w);
                *(float4*)&hs[att][c] = h;
            }
        }
        __syncthreads();

        // ---- A2: logits s[t][k] = sum_c h[t][c] * w2[k][c], 2-t interleave ----
        for (int tp = 0; tp < TILE; tp += 2) {
            float4 a0 = *(const float4*)&hs[tp][c0];
            float4 a1 = *(const float4*)&hs[tp][c0 + 4];
            float4 b0 = *(const float4*)&hs[tp + 1][c0];
            float4 b1v = *(const float4*)&hs[tp + 1][c0 + 4];
            float pa[4], pb[4];
#pragma unroll
            for (int i = 0; i < 4; ++i) {
                float4 u = w2r[i][0], v = w2r[i][1];
                pa[i] = a0.x * u.x + a0.y * u.y + a0.z * u.z + a0.w * u.w
                      + a1.x * v.x + a1.y * v.y + a1.z * v.z + a1.w * v.w;
                pb[i] = b0.x * u.x + b0.y * u.y + b0.z * u.z + b0.w * u.w
                      + b1v.x * v.x + b1v.y * v.y + b1v.z * v.z + b1v.w * v.w;
            }
#pragma unroll
            for (int m = 1; m < 16; m <<= 1) {
#pragma unroll
                for (int i = 0; i < 4; ++i) {
                    pa[i] += __shfl_xor(pa[i], m, 64);
                    pb[i] += __shfl_xor(pb[i], m, 64);
                }
            }
            if (cc == 0) {
                float4 sa, sb;
                sa.x = fmaxf(0.f, pa[0] * sc2[0] + sh2[0]);
                sa.y = fmaxf(0.f, pa[1] * sc2[1] + sh2[1]);
                sa.z = fmaxf(0.f, pa[2] * sc2[2] + sh2[2]);
                sa.w = fmaxf(0.f, pa[3] * sc2[3] + sh2[3]);
                sb.x = fmaxf(0.f, pb[0] * sc2[0] + sh2[0]);
                sb.y = fmaxf(0.f, pb[1] * sc2[1] + sh2[1]);
                sb.z = fmaxf(0.f, pb[2] * sc2[2] + sh2[2]);
                sb.w = fmaxf(0.f, pb[3] * sc2[3] + sh2[3]);
                *(float4*)&atile[tp][k0] = sa;
                *(float4*)&atile[tp + 1][k0] = sb;
            }
        }
        __syncthreads();

        // ---- softmax over k (8 lanes per t, 8 k each) ----
        {
            const int tt = tid >> 3;
            const int kg = (tid & 7) * 8;
            const int t = tbase + tt;
            float4 e0 = *(const float4*)&atile[tt][kg];
            float4 e1 = *(const float4*)&atile[tt][kg + 4];
            if (t < L) {
                float mx = fmaxf(fmaxf(fmaxf(e0.x, e0.y), fmaxf(e0.z, e0.w)),
                                 fmaxf(fmaxf(e1.x, e1.y), fmaxf(e1.z, e1.w)));
#pragma unroll
                for (int m = 1; m < 8; m <<= 1) mx = fmaxf(mx, __shfl_xor(mx, m, 64));
                e0.x = __expf(e0.x - mx); e0.y = __expf(e0.y - mx);
                e0.z = __expf(e0.z - mx); e0.w = __expf(e0.w - mx);
                e1.x = __expf(e1.x - mx); e1.y = __expf(e1.y - mx);
                e1.z = __expf(e1.z - mx); e1.w = __expf(e1.w - mx);
                float se = (e0.x + e0.y) + (e0.z + e0.w) + (e1.x + e1.y) + (e1.z + e1.w);
#pragma unroll
                for (int m = 1; m < 8; m <<= 1) se += __shfl_xor(se, m, 64);
                float inv = 1.0f / se;
                e0.x *= inv; e0.y *= inv; e0.z *= inv; e0.w *= inv;
                e1.x *= inv; e1.y *= inv; e1.z *= inv; e1.w *= inv;
            } else {
                e0.x = e0.y = e0.z = e0.w = 1.0f / 64.0f;
                e1.x = e1.y = e1.z = e1.w = 1.0f / 64.0f;
            }
            *(float4*)&atile[tt][kg] = e0;
            *(float4*)&atile[tt][kg + 4] = e1;
        }
        __syncthreads();

        // ---- B: vlad accumulation (x from global, rn folded into a) ----
#pragma unroll 4
        for (int tt = 0; tt < TILE; ++tt) {
            float r = rtile[tt];
            float4 av = *(const float4*)&atile[tt][k0];
            const float* xg = xb + (size_t)(tbase + tt) * C_ + c0;
            float4 x0 = *(const float4*)&xg[0];
            float4 x1 = *(const float4*)&xg[4];
            float ar[4] = {av.x * r, av.y * r, av.z * r, av.w * r};
            float xx[8] = {x0.x, x0.y, x0.z, x0.w, x1.x, x1.y, x1.z, x1.w};
#pragma unroll
            for (int i = 0; i < 4; ++i)
#pragma unroll
                for (int j = 0; j < 8; ++j) acc[i][j] += ar[i] * xx[j];
        }
        if (tid < 64) {
#pragma unroll 8
            for (int tt = 0; tt < TILE; ++tt) asum += atile[tt][tid];
        }
        __syncthreads();
    }

    float* vlad = ws + WS_VLAD + (size_t)n * (K_ * C_);
#pragma unroll
    for (int i = 0; i < 4; ++i)
#pragma unroll
        for (int j = 0; j < 8; ++j)
            atomicAdd(&vlad[(k0 + i) * C_ + c0 + j], acc[i][j]);
    if (tid < 64) atomicAdd(&ws[WS_ASUM + n * K_ + tid], asum);
}

// per (n,k) row: subtract asum*centroid, intra-L2-normalize, accumulate gsum
__global__ void finalize_k(const float* __restrict__ cent, float* __restrict__ ws,
                           float* __restrict__ out) {
    int row = blockIdx.x * 4 + (threadIdx.x >> 6);  // n*64 + k
    int lane = threadIdx.x & 63;
    int n = row >> 6, k = row & 63;
    const float* v = ws + WS_VLAD + (size_t)row * C_;
    float as = ws[WS_ASUM + row];
    float y0 = v[lane] - as * cent[k * C_ + lane];
    float y1 = v[lane + 64] - as * cent[k * C_ + lane + 64];
    float ss = y0 * y0 + y1 * y1;
#pragma unroll
    for (int m = 1; m < 64; m <<= 1) ss += __shfl_xor(ss, m, 64);
    float rs = 1.0f / fmaxf(sqrtf(ss), 1e-12f);
    out[(size_t)row * C_ + lane] = y0 * rs;
    out[(size_t)row * C_ + lane + 64] = y1 * rs;
    if (lane == 0) atomicAdd(&ws[WS_GSUM + n], ss * rs * rs);
}

__global__ void gscale_k(float* __restrict__ out, const float* __restrict__ ws) {
    int idx = blockIdx.x * 256 + threadIdx.x;  // < N*K*C
    int n = idx >> 13;
    float g = ws[WS_GSUM + n];
    out[idx] *= 1.0f / fmaxf(sqrtf(g), 1e-12f);
}

extern "C" void kernel_launch(void* const* d_in, const int* in_sizes, int n_in,
                              void* d_out, int out_size, void* d_ws, size_t ws_size,
                              hipStream_t stream) {
    const float* x       = (const float*)d_in[0];
    const float* conv1_w = (const float*)d_in[1];
    const float* bn1_g   = (const float*)d_in[2];
    const float* bn1_b   = (const float*)d_in[3];
    const float* bn1_m   = (const float*)d_in[4];
    const float* bn1_v   = (const float*)d_in[5];
    const float* bn2_w2  = (const float*)d_in[6];
    const float* conv2_b = (const float*)d_in[7];
    const float* bn2_g   = (const float*)d_in[8];
    const float* bn2_b   = (const float*)d_in[9];
    const float* bn2_m   = (const float*)d_in[10];
    const float* bn2_v   = (const float*)d_in[11];
    const float* cent    = (const float*)d_in[12];
    const int*   length  = (const int*)d_in[13];
    float* out = (float*)d_out;
    float* ws  = (float*)d_ws;

    zero_ws<<<(WS_ZEND + 255) / 256, 256, 0, stream>>>(ws);
    rnorm_k<<<N_ * T_ / 4, 256, 0, stream>>>(x, ws);
    main_k<<<N_ * BPN, 256, 0, stream>>>(x, conv1_w, bn1_g, bn1_b, bn1_m, bn1_v,
                                         bn2_w2, conv2_b, bn2_g, bn2_b, bn2_m, bn2_v,
                                         length, ws);
    finalize_k<<<(N_ * K_) / 4, 256, 0, stream>>>(cent, ws, out);
    gscale_k<<<(N_ * K_ * C_) / 256, 256, 0, stream>>>(out, ws);
}

// Round 3
// 208.712 us; speedup vs baseline: 1.8971x; 1.8971x over previous
//
#include <hip/hip_runtime.h>
#include <math.h>

#define N_ 16
#define T_ 8192
#define C_ 128
#define K_ 64

#define BPN 32    // blocks per n
#define TPB 256   // t per block
#define TILE 16   // t per wave-tile
#define SUP 64    // t per super-tile (4 waves x TILE)

// ws layout in floats
#define WS_VLAD 0              // N*K*C = 131072
#define WS_ASUM 131072         // N*K
#define WS_GSUM 132096         // N
#define WS_ZEND 132608

typedef __attribute__((ext_vector_type(8))) short short8;
typedef __attribute__((ext_vector_type(4))) float f32x4;

__device__ __forceinline__ uint bfr(float f) {          // fp32 -> bf16 (RNE)
    uint u = __float_as_uint(f);
    return (u + 0x7fffu + ((u >> 16) & 1u)) >> 16;
}
__device__ __forceinline__ uint pack2(float lo, float hi) {
    return bfr(lo) | (bfr(hi) << 16);
}
__device__ __forceinline__ float lo16(uint u) { return __uint_as_float(u << 16); }
__device__ __forceinline__ float hi16(uint u) { return __uint_as_float(u & 0xffff0000u); }

__global__ void zero_ws(float* ws) {
    int i = blockIdx.x * 256 + threadIdx.x;
    if (i < WS_ZEND) ws[i] = 0.0f;
}

// Fused: rnorm -> normalize -> dwconv3+bn1+relu -> logits (MFMA, split-bf16)
// -> bn2+relu+mask+softmax -> vlad accumulation (fp32 VALU) + asum.
__global__ __launch_bounds__(256, 2) void main_k(
    const float* __restrict__ x,
    const float* __restrict__ conv1_w,
    const float* __restrict__ bn1_g, const float* __restrict__ bn1_b,
    const float* __restrict__ bn1_m, const float* __restrict__ bn1_v,
    const float* __restrict__ conv2_w, const float* __restrict__ conv2_b,
    const float* __restrict__ bn2_g, const float* __restrict__ bn2_b,
    const float* __restrict__ bn2_m, const float* __restrict__ bn2_v,
    const int* __restrict__ length,
    float* __restrict__ ws) {

    // bf16 tiles, row strides: h/x 272B (136 bf16), a 136B (68 bf16)
    __shared__ __align__(16) uint h_lds[4][TILE * 68];
    __shared__ __align__(16) uint x_lds[4][TILE * 68];
    __shared__ __align__(16) uint a_lds[4][TILE * 34];
    __shared__ float rn_lds[TPB + 2];

    const int tid = threadIdx.x;
    const int lane = tid & 63;
    const int w = tid >> 6;
    const int n = blockIdx.x >> 5;            // / BPN
    const int tb = (blockIdx.x & 31) * TPB;
    const float* xb = x + (size_t)n * T_ * C_;
    const int L = length[n];

    // ---- preamble: fused rnorm for rows tb-1 .. tb+TPB ----
    for (int idx = tid; idx < TPB + 2; idx += 256) {
        int g = tb - 1 + idx;
        float v = 0.f;
        if (g >= 0 && g < T_) {
            const float* xr = xb + (size_t)g * C_;
            float ss = 0.f;
            for (int c = 0; c < C_; c += 4) {
                float4 q = *(const float4*)&xr[c];
                ss += q.x * q.x + q.y * q.y + q.z * q.z + q.w * q.w;
            }
            v = 1.0f / fmaxf(sqrtf(ss), 1e-12f);
        }
        rn_lds[idx] = v;
    }

    // ---- per-lane conv1/bn1 params for its c-pair (scale1 folded in) ----
    const int cl = lane * 2;
    float s1x = bn1_g[cl] * rsqrtf(bn1_v[cl] + 1e-5f);
    float s1y = bn1_g[cl + 1] * rsqrtf(bn1_v[cl + 1] + 1e-5f);
    float wax = conv1_w[cl * 9 + 1] * s1x, way = conv1_w[(cl + 1) * 9 + 1] * s1y;
    float wbx = conv1_w[cl * 9 + 4] * s1x, wby = conv1_w[(cl + 1) * 9 + 4] * s1y;
    float wcx = conv1_w[cl * 9 + 7] * s1x, wcy = conv1_w[(cl + 1) * 9 + 7] * s1y;
    float sbx = bn1_b[cl] - bn1_m[cl] * s1x, sby = bn1_b[cl + 1] - bn1_m[cl + 1] * s1y;

    // ---- w2 A-fragments in registers (bn2 scale folded; hi/lo bf16 split) ----
    const int fr = lane & 15, fg = lane >> 4;
    short8 w2h[4][4], w2l[4][4];   // [Mtile][Kstep]
#pragma unroll
    for (int m = 0; m < 4; ++m) {
        int k = m * 16 + fr;
        float sck = bn2_g[k] * rsqrtf(bn2_v[k] + 1e-5f);
        const float* wr = conv2_w + k * C_;
#pragma unroll
        for (int q = 0; q < 4; ++q) {
            int cb = q * 32 + fg * 8;
            short8 hi8, lo8;
#pragma unroll
            for (int j = 0; j < 8; ++j) {
                float v = wr[cb + j] * sck;
                uint h = bfr(v);
                hi8[j] = (short)h;
                lo8[j] = (short)bfr(v - __uint_as_float(h << 16));
            }
            w2h[m][q] = hi8;
            w2l[m][q] = lo8;
        }
    }
    // sh2 in softmax register layout: k = m*16 + fg*4 + r
    float sh2r[16];
#pragma unroll
    for (int m = 0; m < 4; ++m)
#pragma unroll
        for (int r = 0; r < 4; ++r) {
            int k = m * 16 + fg * 4 + r;
            float s = bn2_g[k] * rsqrtf(bn2_v[k] + 1e-5f);
            sh2r[m * 4 + r] = s * conv2_b[k] + bn2_b[k] - bn2_m[k] * s;
        }

    const int kk = tid >> 4, cc = tid & 15;   // phase-B tile: 4k x 8c
    float acc[4][8];
#pragma unroll
    for (int i = 0; i < 4; ++i)
#pragma unroll
        for (int j = 0; j < 8; ++j) acc[i][j] = 0.f;
    float asum4[4] = {0.f, 0.f, 0.f, 0.f};

    __syncthreads();

    for (int s = 0; s < TPB / SUP; ++s) {
        const int t0 = tb + s * SUP + w * TILE;
        const bool full = (t0 < L);           // wave-uniform
        uint* hw = h_lds[w];
        uint* xw = x_lds[w];
        uint* aw = a_lds[w];

        if (full) {
            // ---- A1: rolling 3-row conv over this wave's 16 t ----
            float xnmx, xnmy, xncx, xncy;
            {
                float2 xm = {0.f, 0.f};
                if (t0 > 0) xm = *(const float2*)(xb + (size_t)(t0 - 1) * C_ + cl);
                float rm = rn_lds[t0 - tb];
                xnmx = xm.x * rm; xnmy = xm.y * rm;
                float2 xc = *(const float2*)(xb + (size_t)t0 * C_ + cl);
                float rc = rn_lds[t0 - tb + 1];
                xncx = xc.x * rc; xncy = xc.y * rc;
            }
#pragma unroll
            for (int tl = 0; tl < TILE; ++tl) {
                int tn = t0 + tl + 1;
                float2 xp = {0.f, 0.f};
                if (tn < T_) xp = *(const float2*)(xb + (size_t)tn * C_ + cl);
                float rp = rn_lds[tn - tb + 1];
                float xnpx = xp.x * rp, xnpy = xp.y * rp;
                float hx = fmaxf(0.f, xnmx * wax + xncx * wbx + xnpx * wcx + sbx);
                float hy = fmaxf(0.f, xnmy * way + xncy * wby + xnpy * wcy + sby);
                hw[tl * 68 + lane] = pack2(hx, hy);
                xw[tl * 68 + lane] = pack2(xncx, xncy);
                xnmx = xncx; xnmy = xncy; xncx = xnpx; xncy = xnpy;
            }

            // ---- logits via MFMA: S[k][t] = sum_c w2'[k][c] h[t][c] ----
            f32x4 accL[4];
#pragma unroll
            for (int m = 0; m < 4; ++m) accL[m] = (f32x4){0.f, 0.f, 0.f, 0.f};
            const char* hb = (const char*)hw;
            const int fro = fr * 272 + fg * 16;
#pragma unroll
            for (int q = 0; q < 4; ++q) {
                short8 hf = *(const short8*)(hb + fro + q * 64);
                accL[0] = __builtin_amdgcn_mfma_f32_16x16x32_bf16(w2h[0][q], hf, accL[0], 0, 0, 0);
                accL[1] = __builtin_amdgcn_mfma_f32_16x16x32_bf16(w2h[1][q], hf, accL[1], 0, 0, 0);
                accL[2] = __builtin_amdgcn_mfma_f32_16x16x32_bf16(w2h[2][q], hf, accL[2], 0, 0, 0);
                accL[3] = __builtin_amdgcn_mfma_f32_16x16x32_bf16(w2h[3][q], hf, accL[3], 0, 0, 0);
                accL[0] = __builtin_amdgcn_mfma_f32_16x16x32_bf16(w2l[0][q], hf, accL[0], 0, 0, 0);
                accL[1] = __builtin_amdgcn_mfma_f32_16x16x32_bf16(w2l[1][q], hf, accL[1], 0, 0, 0);
                accL[2] = __builtin_amdgcn_mfma_f32_16x16x32_bf16(w2l[2][q], hf, accL[2], 0, 0, 0);
                accL[3] = __builtin_amdgcn_mfma_f32_16x16x32_bf16(w2l[3][q], hf, accL[3], 0, 0, 0);
            }

            // ---- bn2 + relu + mask + softmax over k (col t = fr) ----
            int t = t0 + fr;
            float v[16];
#pragma unroll
            for (int m = 0; m < 4; ++m)
#pragma unroll
                for (int r = 0; r < 4; ++r)
                    v[m * 4 + r] = fmaxf(0.f, accL[m][r] + sh2r[m * 4 + r]);
            if (t < L) {
                float mx = v[0];
#pragma unroll
                for (int i = 1; i < 16; ++i) mx = fmaxf(mx, v[i]);
                mx = fmaxf(mx, __shfl_xor(mx, 16, 64));
                mx = fmaxf(mx, __shfl_xor(mx, 32, 64));
                float se = 0.f;
#pragma unroll
                for (int i = 0; i < 16; ++i) { v[i] = __expf(v[i] - mx); se += v[i]; }
                se += __shfl_xor(se, 16, 64);
                se += __shfl_xor(se, 32, 64);
                float inv = 1.0f / se;
#pragma unroll
                for (int i = 0; i < 16; ++i) v[i] *= inv;
            } else {
#pragma unroll
                for (int i = 0; i < 16; ++i) v[i] = 0.015625f;
            }
#pragma unroll
            for (int m = 0; m < 4; ++m) {
                uint2 p;
                p.x = pack2(v[m * 4 + 0], v[m * 4 + 1]);
                p.y = pack2(v[m * 4 + 2], v[m * 4 + 3]);
                *(uint2*)&aw[fr * 34 + m * 8 + fg * 2] = p;
            }
        } else {
            // fully masked tile: only xn needed; a = 1/64 exactly
#pragma unroll
            for (int tl = 0; tl < TILE; ++tl) {
                float2 xc = *(const float2*)(xb + (size_t)(t0 + tl) * C_ + cl);
                float rc = rn_lds[t0 + tl - tb + 1];
                xw[tl * 68 + lane] = pack2(xc.x * rc, xc.y * rc);
            }
            for (int idx = lane; idx < TILE * 34; idx += 64) aw[idx] = 0x3C803C80u;
        }
        __syncthreads();

        // ---- phase B: vlad += a * xn over the 64-t super-tile ----
#pragma unroll 4
        for (int tt = 0; tt < SUP; ++tt) {
            const uint* aws = a_lds[tt >> 4];
            const uint* xws = x_lds[tt >> 4];
            int tl = tt & 15;
            uint2 au = *(const uint2*)&aws[tl * 34 + kk * 2];
            uint4 xu = *(const uint4*)&xws[tl * 68 + cc * 4];
            float a0 = lo16(au.x), a1 = hi16(au.x), a2 = lo16(au.y), a3 = hi16(au.y);
            float xv[8] = {lo16(xu.x), hi16(xu.x), lo16(xu.y), hi16(xu.y),
                           lo16(xu.z), hi16(xu.z), lo16(xu.w), hi16(xu.w)};
            asum4[0] += a0; asum4[1] += a1; asum4[2] += a2; asum4[3] += a3;
#pragma unroll
            for (int j = 0; j < 8; ++j) {
                acc[0][j] += a0 * xv[j];
                acc[1][j] += a1 * xv[j];
                acc[2][j] += a2 * xv[j];
                acc[3][j] += a3 * xv[j];
            }
        }
        __syncthreads();
    }

    float* vlad = ws + WS_VLAD + (size_t)n * (K_ * C_);
#pragma unroll
    for (int i = 0; i < 4; ++i)
#pragma unroll
        for (int j = 0; j < 8; ++j)
            atomicAdd(&vlad[(kk * 4 + i) * C_ + cc * 8 + j], acc[i][j]);
    if (cc == 0) {
#pragma unroll
        for (int i = 0; i < 4; ++i)
            atomicAdd(&ws[WS_ASUM + n * K_ + kk * 4 + i], asum4[i]);
    }
}

// per (n,k) row: subtract asum*centroid, intra-L2-normalize, accumulate gsum
__global__ void finalize_k(const float* __restrict__ cent, float* __restrict__ ws,
                           float* __restrict__ out) {
    int row = blockIdx.x * 4 + (threadIdx.x >> 6);  // n*64 + k
    int lane = threadIdx.x & 63;
    int n = row >> 6, k = row & 63;
    const float* v = ws + WS_VLAD + (size_t)row * C_;
    float as = ws[WS_ASUM + row];
    float y0 = v[lane] - as * cent[k * C_ + lane];
    float y1 = v[lane + 64] - as * cent[k * C_ + lane + 64];
    float ss = y0 * y0 + y1 * y1;
#pragma unroll
    for (int m = 1; m < 64; m <<= 1) ss += __shfl_xor(ss, m, 64);
    float rs = 1.0f / fmaxf(sqrtf(ss), 1e-12f);
    out[(size_t)row * C_ + lane] = y0 * rs;
    out[(size_t)row * C_ + lane + 64] = y1 * rs;
    if (lane == 0) atomicAdd(&ws[WS_GSUM + n], ss * rs * rs);
}

__global__ void gscale_k(float* __restrict__ out, const float* __restrict__ ws) {
    int idx = blockIdx.x * 256 + threadIdx.x;  // < N*K*C
    int n = idx >> 13;
    float g = ws[WS_GSUM + n];
    out[idx] *= 1.0f / fmaxf(sqrtf(g), 1e-12f);
}

extern "C" void kernel_launch(void* const* d_in, const int* in_sizes, int n_in,
                              void* d_out, int out_size, void* d_ws, size_t ws_size,
                              hipStream_t stream) {
    const float* x       = (const float*)d_in[0];
    const float* conv1_w = (const float*)d_in[1];
    const float* bn1_g   = (const float*)d_in[2];
    const float* bn1_b   = (const float*)d_in[3];
    const float* bn1_m   = (const float*)d_in[4];
    const float* bn1_v   = (const float*)d_in[5];
    const float* conv2_w = (const float*)d_in[6];
    const float* conv2_b = (const float*)d_in[7];
    const float* bn2_g   = (const float*)d_in[8];
    const float* bn2_b   = (const float*)d_in[9];
    const float* bn2_m   = (const float*)d_in[10];
    const float* bn2_v   = (const float*)d_in[11];
    const float* cent    = (const float*)d_in[12];
    const int*   length  = (const int*)d_in[13];
    float* out = (float*)d_out;
    float* ws  = (float*)d_ws;

    zero_ws<<<(WS_ZEND + 255) / 256, 256, 0, stream>>>(ws);
    main_k<<<N_ * BPN, 256, 0, stream>>>(x, conv1_w, bn1_g, bn1_b, bn1_m, bn1_v,
                                         conv2_w, conv2_b, bn2_g, bn2_b, bn2_m, bn2_v,
                                         length, ws);
    finalize_k<<<(N_ * K_) / 4, 256, 0, stream>>>(cent, ws, out);
    gscale_k<<<(N_ * K_ * C_) / 256, 256, 0, stream>>>(out, ws);
}

// Round 4
// 179.425 us; speedup vs baseline: 2.2068x; 1.1632x over previous
//
#include <hip/hip_runtime.h>
#include <math.h>

#define N_ 16
#define T_ 8192
#define C_ 128
#define K_ 64

#define BPN 64    // blocks per n
#define TPB 128   // t per block
#define TILE 16   // t per wave-tile
#define SUP 64    // t per super-tile (4 waves x TILE)

// ws layout in floats
#define WS_VLAD 0              // N*K*C = 131072
#define WS_ASUM 131072         // N*K
#define WS_GSUM 132096         // N
#define WS_ZEND 132608
#define WS_RNORM 132608        // N*T floats

typedef __attribute__((ext_vector_type(8))) short short8;
typedef __attribute__((ext_vector_type(4))) float f32x4;

__device__ __forceinline__ uint bfr(float f) {          // fp32 -> bf16 (RNE)
    uint u = __float_as_uint(f);
    return (u + 0x7fffu + ((u >> 16) & 1u)) >> 16;
}
__device__ __forceinline__ float bflo(uint h) { return __uint_as_float(h << 16); }

__global__ void zero_ws(float* ws) {
    int i = blockIdx.x * 256 + threadIdx.x;
    if (i < WS_ZEND) ws[i] = 0.0f;
}

// 1 / max(||x[n,t,:]||, 1e-12), one wave per (n,t) row
__global__ void rnorm_k(const float* __restrict__ x, float* __restrict__ ws) {
    int row = blockIdx.x * 4 + (threadIdx.x >> 6);
    int lane = threadIdx.x & 63;
    const float* xr = x + (size_t)row * C_;
    float a = xr[lane], b = xr[lane + 64];
    float ss = a * a + b * b;
#pragma unroll
    for (int m = 1; m < 64; m <<= 1) ss += __shfl_xor(ss, m, 64);
    if (lane == 0) ws[WS_RNORM + row] = 1.0f / fmaxf(sqrtf(ss), 1e-12f);
}

// Fused: normalize -> dwconv3+bn1+relu -> logits (MFMA) -> bn2+relu+mask
// -> softmax -> vlad GEMM (MFMA, bf16 a/xn, fp32 acc) + asum.
__global__ __launch_bounds__(256, 2) void main_k(
    const float* __restrict__ x,
    const float* __restrict__ conv1_w,
    const float* __restrict__ bn1_g, const float* __restrict__ bn1_b,
    const float* __restrict__ bn1_m, const float* __restrict__ bn1_v,
    const float* __restrict__ conv2_w, const float* __restrict__ conv2_b,
    const float* __restrict__ bn2_g, const float* __restrict__ bn2_b,
    const float* __restrict__ bn2_m, const float* __restrict__ bn2_v,
    const int* __restrict__ length,
    float* __restrict__ ws) {

    // h: per-wave [16t][136c-pad] bf16 rows (272B, 16B-aligned)
    __shared__ __align__(16) ushort h_s[4][TILE * 136];      // 17408 B
    // xn/a: t-minor, 16B chunks, XOR-swizzled: chunk(row,j) = row*8 + (j^(row&7))
    __shared__ __align__(16) uint4 xn4[C_ * 8];              // 16384 B
    __shared__ __align__(16) ushort a_s[K_ * 64];            // 8192 B
    __shared__ float rn_lds[TPB + 2];

    const int tid = threadIdx.x;
    const int lane = tid & 63;
    const int w = tid >> 6;
    const int fr = lane & 15, fg = lane >> 4;
    const int n = blockIdx.x >> 6;                 // / BPN
    const int tb = (blockIdx.x & (BPN - 1)) * TPB;
    const float* xb = x + (size_t)n * T_ * C_;
    const float* rng = ws + WS_RNORM + (size_t)n * T_;
    const int L = length[n];

    for (int i = tid; i < TPB + 2; i += 256) {
        int t = tb - 1 + i;
        rn_lds[i] = (t >= 0 && t < T_) ? rng[t] : 0.f;
    }

    // conv1/bn1 params for c = lane, lane+64 (bn1 scale folded)
    float wa[2], wbv[2], wcv[2], sbv[2];
#pragma unroll
    for (int p = 0; p < 2; ++p) {
        int c = lane + p * 64;
        float s1 = bn1_g[c] * rsqrtf(bn1_v[c] + 1e-5f);
        wa[p] = conv1_w[c * 9 + 1] * s1;
        wbv[p] = conv1_w[c * 9 + 4] * s1;
        wcv[p] = conv1_w[c * 9 + 7] * s1;
        sbv[p] = bn1_b[c] - bn1_m[c] * s1;
    }

    // w2 A-fragments (bf16, bn2 scale folded)
    short8 w2h[4][4];
#pragma unroll
    for (int m = 0; m < 4; ++m) {
        int k = m * 16 + fr;
        float sck = bn2_g[k] * rsqrtf(bn2_v[k] + 1e-5f);
        const float* wr = conv2_w + k * C_;
#pragma unroll
        for (int q = 0; q < 4; ++q) {
            short8 v8;
#pragma unroll
            for (int j = 0; j < 8; ++j)
                v8[j] = (short)bfr(wr[q * 32 + fg * 8 + j] * sck);
            w2h[m][q] = v8;
        }
    }
    // bias in softmax register layout: k = m*16 + fg*4 + r
    float sh2r[16];
#pragma unroll
    for (int m = 0; m < 4; ++m)
#pragma unroll
        for (int r = 0; r < 4; ++r) {
            int k = m * 16 + fg * 4 + r;
            float s = bn2_g[k] * rsqrtf(bn2_v[k] + 1e-5f);
            sh2r[m * 4 + r] = s * conv2_b[k] + bn2_b[k] - bn2_m[k] * s;
        }

    f32x4 accB[8];
#pragma unroll
    for (int cb = 0; cb < 8; ++cb) accB[cb] = (f32x4){0.f, 0.f, 0.f, 0.f};
    float asum_reg[16];
#pragma unroll
    for (int i = 0; i < 16; ++i) asum_reg[i] = 0.f;
    int mcnt = 0;

    __syncthreads();

    for (int s = 0; s < TPB / SUP; ++s) {
        const int t0 = tb + s * SUP + w * TILE;
        const bool full = (t0 < L);
        const int tl0 = t0 - tb;
        ushort* hw = h_s[w];

        // ---- A1: rolling 3-tap conv along t, lane = channel ----
#pragma unroll
        for (int p = 0; p < 2; ++p) {
            const int c = lane + p * 64;
            float xnm = 0.f;
            if (t0 > 0) xnm = xb[(size_t)(t0 - 1) * C_ + c] * rn_lds[tl0];
            float xnc = xb[(size_t)t0 * C_ + c] * rn_lds[tl0 + 1];
            uint pk[8];
#pragma unroll
            for (int tl = 0; tl < TILE; ++tl) {
                int tn = t0 + tl + 1;
                float xnp = 0.f;
                if (tn < T_) xnp = xb[(size_t)tn * C_ + c] * rn_lds[tl0 + tl + 2];
                if (full) {
                    float h = fmaxf(0.f, xnm * wa[p] + xnc * wbv[p] + xnp * wcv[p] + sbv[p]);
                    hw[tl * 136 + c] = (ushort)bfr(h);
                }
                uint b = bfr(xnc);
                if (tl & 1) pk[tl >> 1] |= b << 16; else pk[tl >> 1] = b;
                xnm = xnc; xnc = xnp;
            }
            uint4 lo4, hi4;
            lo4.x = pk[0]; lo4.y = pk[1]; lo4.z = pk[2]; lo4.w = pk[3];
            hi4.x = pk[4]; hi4.y = pk[5]; hi4.z = pk[6]; hi4.w = pk[7];
            xn4[c * 8 + ((w * 2) ^ (c & 7))] = lo4;
            xn4[c * 8 + ((w * 2 + 1) ^ (c & 7))] = hi4;
        }

        if (full) {
            // ---- logits MFMA: S[k][t] = sum_c w2'[k][c] h[t][c] ----
            f32x4 accL[4];
#pragma unroll
            for (int m = 0; m < 4; ++m) accL[m] = (f32x4){0.f, 0.f, 0.f, 0.f};
            const ushort* hb = hw + fr * 136 + fg * 8;
#pragma unroll
            for (int q = 0; q < 4; ++q) {
                short8 hf = *(const short8*)(hb + q * 32);
                accL[0] = __builtin_amdgcn_mfma_f32_16x16x32_bf16(w2h[0][q], hf, accL[0], 0, 0, 0);
                accL[1] = __builtin_amdgcn_mfma_f32_16x16x32_bf16(w2h[1][q], hf, accL[1], 0, 0, 0);
                accL[2] = __builtin_amdgcn_mfma_f32_16x16x32_bf16(w2h[2][q], hf, accL[2], 0, 0, 0);
                accL[3] = __builtin_amdgcn_mfma_f32_16x16x32_bf16(w2h[3][q], hf, accL[3], 0, 0, 0);
            }
            // ---- bn2 + relu + mask + softmax over k (this lane: t = t0+fr) ----
            int t = t0 + fr;
            float v[16];
#pragma unroll
            for (int m = 0; m < 4; ++m)
#pragma unroll
                for (int r = 0; r < 4; ++r)
                    v[m * 4 + r] = fmaxf(0.f, accL[m][r] + sh2r[m * 4 + r]);
            if (t < L) {
                float mx = v[0];
#pragma unroll
                for (int i = 1; i < 16; ++i) mx = fmaxf(mx, v[i]);
                mx = fmaxf(mx, __shfl_xor(mx, 16, 64));
                mx = fmaxf(mx, __shfl_xor(mx, 32, 64));
                float se = 0.f;
#pragma unroll
                for (int i = 0; i < 16; ++i) { v[i] = __expf(v[i] - mx); se += v[i]; }
                se += __shfl_xor(se, 16, 64);
                se += __shfl_xor(se, 32, 64);
                float inv = 1.0f / se;
#pragma unroll
                for (int i = 0; i < 16; ++i) v[i] *= inv;
            } else {
#pragma unroll
                for (int i = 0; i < 16; ++i) v[i] = 0.015625f;
            }
            // write a (bf16) t-minor + accumulate rounded asum
            const int jq = w * 2 + (fr >> 3);
            const int te = fr & 7;
#pragma unroll
            for (int m = 0; m < 4; ++m)
#pragma unroll
                for (int r = 0; r < 4; ++r) {
                    int k = m * 16 + fg * 4 + r;
                    uint hv = bfr(v[m * 4 + r]);
                    a_s[(k * 8 + (jq ^ (k & 7))) * 8 + te] = (ushort)hv;
                    asum_reg[m * 4 + r] += bflo(hv);
                }
        } else {
            // fully masked tile: a = 1/64 (bf16 exact)
            uint4 ones;
            ones.x = ones.y = ones.z = ones.w = 0x3C803C80u;
            *(uint4*)&a_s[(lane * 8 + ((w * 2) ^ (lane & 7))) * 8] = ones;
            *(uint4*)&a_s[(lane * 8 + ((w * 2 + 1) ^ (lane & 7))) * 8] = ones;
            mcnt++;
        }
        __syncthreads();

        // ---- phase B: vlad GEMM on MFMA. wave w owns k-block w ----
#pragma unroll
        for (int tK = 0; tK < 2; ++tK) {
            int ar = w * 16 + fr;
            short8 af = *(const short8*)&a_s[(ar * 8 + ((tK * 4 + fg) ^ (ar & 7))) * 8];
#pragma unroll
            for (int cb = 0; cb < 8; ++cb) {
                int cr = cb * 16 + fr;
                short8 bf = *(const short8*)&xn4[cr * 8 + ((tK * 4 + fg) ^ (cr & 7))];
                accB[cb] = __builtin_amdgcn_mfma_f32_16x16x32_bf16(af, bf, accB[cb], 0, 0, 0);
            }
        }
        __syncthreads();
    }

    float* vlad = ws + WS_VLAD + (size_t)n * (K_ * C_);
#pragma unroll
    for (int cb = 0; cb < 8; ++cb)
#pragma unroll
        for (int r = 0; r < 4; ++r)
            atomicAdd(&vlad[(w * 16 + fg * 4 + r) * C_ + cb * 16 + fr], accB[cb][r]);

#pragma unroll
    for (int i = 0; i < 16; ++i) {
        float v = asum_reg[i];
        v += __shfl_xor(v, 1, 64); v += __shfl_xor(v, 2, 64);
        v += __shfl_xor(v, 4, 64); v += __shfl_xor(v, 8, 64);
        asum_reg[i] = v;
    }
    if (fr == 0) {
#pragma unroll
        for (int i = 0; i < 16; ++i) {
            int k = (i >> 2) * 16 + fg * 4 + (i & 3);
            atomicAdd(&ws[WS_ASUM + n * K_ + k], asum_reg[i] + 0.25f * (float)mcnt);
        }
    }
}

// per (n,k) row: subtract asum*centroid, intra-L2-normalize, accumulate gsum
__global__ void finalize_k(const float* __restrict__ cent, float* __restrict__ ws,
                           float* __restrict__ out) {
    int row = blockIdx.x * 4 + (threadIdx.x >> 6);  // n*64 + k
    int lane = threadIdx.x & 63;
    int n = row >> 6, k = row & 63;
    const float* v = ws + WS_VLAD + (size_t)row * C_;
    float as = ws[WS_ASUM + row];
    float y0 = v[lane] - as * cent[k * C_ + lane];
    float y1 = v[lane + 64] - as * cent[k * C_ + lane + 64];
    float ss = y0 * y0 + y1 * y1;
#pragma unroll
    for (int m = 1; m < 64; m <<= 1) ss += __shfl_xor(ss, m, 64);
    float rs = 1.0f / fmaxf(sqrtf(ss), 1e-12f);
    out[(size_t)row * C_ + lane] = y0 * rs;
    out[(size_t)row * C_ + lane + 64] = y1 * rs;
    if (lane == 0) atomicAdd(&ws[WS_GSUM + n], ss * rs * rs);
}

__global__ void gscale_k(float* __restrict__ out, const float* __restrict__ ws) {
    int idx = blockIdx.x * 256 + threadIdx.x;  // < N*K*C
    int n = idx >> 13;
    float g = ws[WS_GSUM + n];
    out[idx] *= 1.0f / fmaxf(sqrtf(g), 1e-12f);
}

extern "C" void kernel_launch(void* const* d_in, const int* in_sizes, int n_in,
                              void* d_out, int out_size, void* d_ws, size_t ws_size,
                              hipStream_t stream) {
    const float* x       = (const float*)d_in[0];
    const float* conv1_w = (const float*)d_in[1];
    const float* bn1_g   = (const float*)d_in[2];
    const float* bn1_b   = (const float*)d_in[3];
    const float* bn1_m   = (const float*)d_in[4];
    const float* bn1_v   = (const float*)d_in[5];
    const float* conv2_w = (const float*)d_in[6];
    const float* conv2_b = (const float*)d_in[7];
    const float* bn2_g   = (const float*)d_in[8];
    const float* bn2_b   = (const float*)d_in[9];
    const float* bn2_m   = (const float*)d_in[10];
    const float* bn2_v   = (const float*)d_in[11];
    const float* cent    = (const float*)d_in[12];
    const int*   length  = (const int*)d_in[13];
    float* out = (float*)d_out;
    float* ws  = (float*)d_ws;

    zero_ws<<<(WS_ZEND + 255) / 256, 256, 0, stream>>>(ws);
    rnorm_k<<<N_ * T_ / 4, 256, 0, stream>>>(x, ws);
    main_k<<<N_ * BPN, 256, 0, stream>>>(x, conv1_w, bn1_g, bn1_b, bn1_m, bn1_v,
                                         conv2_w, conv2_b, bn2_g, bn2_b, bn2_m, bn2_v,
                                         length, ws);
    finalize_k<<<(N_ * K_) / 4, 256, 0, stream>>>(cent, ws, out);
    gscale_k<<<(N_ * K_ * C_) / 256, 256, 0, stream>>>(out, ws);
}